// Round 4
// baseline (189.440 us; speedup 1.0000x reference)
//
#include <hip/hip_runtime.h>
#include <hip/hip_bf16.h>

// Problem constants: B=16, S=1024, D=768, DOUT=256
static constexpr float INV_TEMP = 0.03608439182435161f; // 1/sqrt(768)

typedef __attribute__((ext_vector_type(8))) short bf16x8;
typedef __attribute__((ext_vector_type(4))) float f32x4;
typedef __attribute__((ext_vector_type(8))) unsigned short u16x8;

__device__ __forceinline__ unsigned short f2bf(float f) {
  unsigned u = __float_as_uint(f);
  u += 0x7fffu + ((u >> 16) & 1u);
  return (unsigned short)(u >> 16);
}

__device__ __forceinline__ void async_copy16(const void* g, void* lds) {
  __builtin_amdgcn_global_load_lds(
      (const __attribute__((address_space(1))) unsigned int*)g,
      (__attribute__((address_space(3))) unsigned int*)lds, 16, 0, 0);
}

// ---------------- pack kernels ----------------
__global__ __launch_bounds__(256) void pack_emb(const float* __restrict__ src,
                                                unsigned short* __restrict__ dst) {
  long i = ((long)blockIdx.x * 256 + threadIdx.x) * 8;
  float4 a = *(const float4*)(src + i);
  float4 b = *(const float4*)(src + i + 4);
  u16x8 v;
  v[0] = f2bf(a.x); v[1] = f2bf(a.y); v[2] = f2bf(a.z); v[3] = f2bf(a.w);
  v[4] = f2bf(b.x); v[5] = f2bf(b.y); v[6] = f2bf(b.z); v[7] = f2bf(b.w);
  *(u16x8*)(dst + i) = v;
}

__global__ __launch_bounds__(256) void pack_w(
    const int* __restrict__ isq_p,
    const float* qWq, const float* qbq, const float* qWk, const float* qbk,
    const float* qWv, const float* qbv,
    const float* dWq, const float* dbq, const float* dWk, const float* dbk,
    const float* dWv, const float* dbv,
    unsigned short* __restrict__ WT, float* __restrict__ bias) {
  const int n = blockIdx.x;  // 0..1791
  const int isq = *isq_p;
  const float* W; const float* bsrc; int col, srcN;
  if (n < 768)       { W = isq ? qWq : dWq; bsrc = isq ? qbq : dbq; col = n;        srcN = 768; }
  else if (n < 1536) { W = isq ? qWk : dWk; bsrc = isq ? qbk : dbk; col = n - 768;  srcN = 768; }
  else               { W = isq ? qWv : dWv; bsrc = isq ? qbv : dbv; col = n - 1536; srcN = 256; }
#pragma unroll
  for (int i = 0; i < 3; ++i) {
    int d = threadIdx.x + i * 256;
    WT[(long)n * 768 + d] = f2bf(W[(long)d * srcN + col]);
  }
  if (threadIdx.x == 0) bias[n] = bsrc[col];
}

// ======== merged projection: QK (blocks 0..1535) + VT (1536..1791) ========
// 2-phase 128x128 tile, BK=32, 4 waves, 32 KiB LDS -> 4 blocks/CU overlap.
__global__ __launch_bounds__(256) void proj2(
    const unsigned short* __restrict__ emb_bf,
    const unsigned short* __restrict__ WT,
    const float* __restrict__ bias,
    unsigned short* __restrict__ QK,
    unsigned short* __restrict__ VT) {
  __shared__ unsigned short Ab[2][128 * 32];
  __shared__ unsigned short Bb[2][128 * 32];
  const int id = blockIdx.x;
  const int tid = threadIdx.x, wid = tid >> 6, lane = tid & 63;
  const int isQK = id < 1536;
  long xa, yb;
  const unsigned short* A;
  const unsigned short* BT;
  if (isQK) {
    xa = id & 127; yb = id >> 7;                 // 128 M-tiles x 12 N-tiles
    A = emb_bf + xa * 128 * 768;
    BT = WT + yb * 128 * 768;
  } else {
    int vid = id - 1536;                          // 2 x 128
    xa = vid & 1; yb = vid >> 1;
    A = WT + (long)1536 * 768 + xa * 128 * 768;   // WvT rows
    BT = emb_bf + yb * 128 * 768;
  }
  const int srow = lane >> 2;
  const int skk = (lane & 3) * 8;

  auto stage = [&](int buf, int kt) {
    const unsigned short* As = A + (long)kt * 32;
    const unsigned short* Bs = BT + (long)kt * 32;
#pragma unroll
    for (int i = 0; i < 2; ++i) {
      int c = wid * 2 + i;  // chunk 0..7, 16 rows each
      async_copy16(As + (long)(c * 16 + srow) * 768 + skk, &Ab[buf][c * 512]);
      async_copy16(Bs + (long)(c * 16 + srow) * 768 + skk, &Bb[buf][c * 512]);
    }
  };

  f32x4 acc[4][4] = {};
  stage(0, 0);
  __syncthreads();
  int buf = 0;
  const int wr = wid >> 1, wc = wid & 1;
  const int fr = lane & 15, fq = lane >> 4;
  for (int kt = 0; kt < 24; ++kt) {
    if (kt + 1 < 24) stage(buf ^ 1, kt + 1);
    const unsigned short* Ap = &Ab[buf][(wr * 64 + fr) * 32 + fq * 8];
    const unsigned short* Bp = &Bb[buf][(wc * 64 + fr) * 32 + fq * 8];
    bf16x8 af[4], bfv[4];
#pragma unroll
    for (int mi = 0; mi < 4; ++mi) af[mi] = *(const bf16x8*)(Ap + mi * 16 * 32);
#pragma unroll
    for (int ni = 0; ni < 4; ++ni) bfv[ni] = *(const bf16x8*)(Bp + ni * 16 * 32);
#pragma unroll
    for (int mi = 0; mi < 4; ++mi)
#pragma unroll
      for (int ni = 0; ni < 4; ++ni)
        acc[mi][ni] = __builtin_amdgcn_mfma_f32_16x16x32_bf16(af[mi], bfv[ni], acc[mi][ni], 0, 0, 0);
    __syncthreads();
    buf ^= 1;
  }

#pragma unroll
  for (int mi = 0; mi < 4; ++mi) {
#pragma unroll
    for (int ni = 0; ni < 4; ++ni) {
      const long m = wr * 64 + mi * 16 + fq * 4;
      const long n = wc * 64 + ni * 16 + fr;
      f32x4 v = acc[mi][ni];
      if (isQK) {
        const long gm = xa * 128 + m, gn = yb * 128 + n;
        const float bb = bias[gn];
#pragma unroll
        for (int r = 0; r < 4; ++r) QK[(gm + r) * 1536 + gn] = f2bf(v[r] + bb);
      } else {
        const long gm = xa * 128 + m, gn = yb * 128 + n;
#pragma unroll
        for (int r = 0; r < 4; ++r)
          VT[(gm + r) * 16384 + gn] = f2bf(v[r] + bias[1536 + gm + r]);
      }
    }
  }
}

// ======== fused logits + mask + softmax ========
// Block: 64 Q-rows x full 1024 K-cols of one batch. grid (16 mtiles, 16 batches).
// 2-phase GEMM, BK=32, 8 waves (wave n-slice of 128 cols), acc 4m x 8n.
// LDS: buf{0,1} of [B 1024x32 | A 64x32] bf16 = 136 KiB; red buffers reuse smem.
__global__ __launch_bounds__(512, 2) void logits_sm(
    const unsigned short* __restrict__ QK,
    const int* __restrict__ mask,
    float* __restrict__ attn,
    unsigned short* __restrict__ attnbf) {
  extern __shared__ unsigned short smem[];  // 69632 elems
  const int tid = threadIdx.x, w = tid >> 6, lane = tid & 63;
  const int fr = lane & 15, fq = lane >> 4;
  const int mt = blockIdx.x, b = blockIdx.y;
  const unsigned short* Abase = QK + ((long)b * 1024 + mt * 64) * 1536;       // Q rows
  const unsigned short* Bbase = QK + 768 + (long)b * 1024 * 1536;             // K rows

  auto stage = [&](int buf, int kt) {
    unsigned short* Bl = smem + buf * 34816;
    unsigned short* Al = Bl + 32768;
    const unsigned short* Bs = Bbase + kt * 32;
    const unsigned short* As = Abase + kt * 32;
#pragma unroll
    for (int j = 0; j < 8; ++j) {
      int e = (tid + j * 512) * 8;   // 0..32760
      async_copy16(Bs + (long)(e >> 5) * 1536 + (e & 31), Bl + e);
    }
    if (tid < 256) {
      int e = tid * 8;
      async_copy16(As + (long)(e >> 5) * 1536 + (e & 31), Al + e);
    }
  };

  f32x4 acc[4][8];
#pragma unroll
  for (int m = 0; m < 4; ++m)
#pragma unroll
    for (int n = 0; n < 8; ++n) acc[m][n] = f32x4{0.f, 0.f, 0.f, 0.f};

  stage(0, 0);
  __syncthreads();
  int buf = 0;
  for (int kt = 0; kt < 24; ++kt) {
    if (kt + 1 < 24) stage(buf ^ 1, kt + 1);
    const unsigned short* Bl = smem + buf * 34816;
    const unsigned short* Al = Bl + 32768;
    const unsigned short* Ap = Al + fr * 32 + fq * 8;
    const unsigned short* Bp = Bl + (w * 128 + fr) * 32 + fq * 8;
    bf16x8 a[4], bv[8];
#pragma unroll
    for (int m = 0; m < 4; ++m) a[m] = *(const bf16x8*)(Ap + m * 16 * 32);
#pragma unroll
    for (int n = 0; n < 8; ++n) bv[n] = *(const bf16x8*)(Bp + n * 16 * 32);
#pragma unroll
    for (int m = 0; m < 4; ++m)
#pragma unroll
      for (int n = 0; n < 8; ++n)
        acc[m][n] = __builtin_amdgcn_mfma_f32_16x16x32_bf16(a[m], bv[n], acc[m][n], 0, 0, 0);
    __syncthreads();
    buf ^= 1;
  }

  // ---- epilogue: scale, mask, row softmax across 8 waves ----
  float* redm = (float*)smem;          // [64][8]
  float* reds = (float*)smem + 512;    // [64][8]
  int mk[8];
#pragma unroll
  for (int n = 0; n < 8; ++n) mk[n] = mask[(long)b * 1024 + w * 128 + n * 16 + fr];
#pragma unroll
  for (int m = 0; m < 4; ++m)
#pragma unroll
    for (int n = 0; n < 8; ++n)
#pragma unroll
      for (int r = 0; r < 4; ++r)
        acc[m][n][r] = mk[n] ? acc[m][n][r] * INV_TEMP : -1e9f;

  // wave-partial row max (reduce over n in-reg, over fr via shfl_xor 1,2,4,8)
#pragma unroll
  for (int m = 0; m < 4; ++m)
#pragma unroll
    for (int r = 0; r < 4; ++r) {
      float t = acc[m][0][r];
#pragma unroll
      for (int n = 1; n < 8; ++n) t = fmaxf(t, acc[m][n][r]);
      t = fmaxf(t, __shfl_xor(t, 1));
      t = fmaxf(t, __shfl_xor(t, 2));
      t = fmaxf(t, __shfl_xor(t, 4));
      t = fmaxf(t, __shfl_xor(t, 8));
      if (fr == 0) redm[(m * 16 + fq * 4 + r) * 8 + w] = t;
    }
  __syncthreads();

  // global max, exp, wave-partial sum
#pragma unroll
  for (int m = 0; m < 4; ++m)
#pragma unroll
    for (int r = 0; r < 4; ++r) {
      const int row = m * 16 + fq * 4 + r;
      f32x4 q0 = *(const f32x4*)&redm[row * 8];
      f32x4 q1 = *(const f32x4*)&redm[row * 8 + 4];
      float M = fmaxf(fmaxf(fmaxf(q0[0], q0[1]), fmaxf(q0[2], q0[3])),
                      fmaxf(fmaxf(q1[0], q1[1]), fmaxf(q1[2], q1[3])));
      float s = 0.f;
#pragma unroll
      for (int n = 0; n < 8; ++n) {
        acc[m][n][r] = __expf(acc[m][n][r] - M);
        s += acc[m][n][r];
      }
      s += __shfl_xor(s, 1);
      s += __shfl_xor(s, 2);
      s += __shfl_xor(s, 4);
      s += __shfl_xor(s, 8);
      if (fr == 0) reds[row * 8 + w] = s;
    }
  __syncthreads();

  // normalize + write attn f32 (d_out) and attnbf
  float* arow = attn + (long)b * 1024 * 1024 + (long)mt * 64 * 1024;
  unsigned short* brow = attnbf + (long)b * 1024 * 1024 + (long)mt * 64 * 1024;
#pragma unroll
  for (int m = 0; m < 4; ++m)
#pragma unroll
    for (int r = 0; r < 4; ++r) {
      const int row = m * 16 + fq * 4 + r;
      f32x4 q0 = *(const f32x4*)&reds[row * 8];
      f32x4 q1 = *(const f32x4*)&reds[row * 8 + 4];
      float S = (q0[0] + q0[1] + q0[2] + q0[3]) + (q1[0] + q1[1] + q1[2] + q1[3]);
      const float inv = 1.0f / S;
#pragma unroll
      for (int n = 0; n < 8; ++n) {
        const long col = w * 128 + n * 16 + fr;
        const float o = acc[m][n][r] * inv;
        arow[(long)row * 1024 + col] = o;
        brow[(long)row * 1024 + col] = f2bf(o);
      }
    }
}

// ======== PV: 128x64 tiles, 512 blocks ========
__global__ __launch_bounds__(256) void gemm_pv(
    const unsigned short* __restrict__ attnbf,   // [16][1024][1024]
    const unsigned short* __restrict__ VT,       // [256][16384]
    float* __restrict__ out) {                   // [16][1024][256]
  __shared__ unsigned short Ab[2][128 * 32];
  __shared__ unsigned short Bb[2][64 * 32];
  const int tid = threadIdx.x, wid = tid >> 6, lane = tid & 63;
  const int bz = blockIdx.z;
  const unsigned short* A = attnbf + (long)bz * 1024 * 1024 + (long)blockIdx.x * 128 * 1024;
  const unsigned short* BT = VT + (long)bz * 1024 + (long)blockIdx.y * 64 * 16384;
  const int srow = lane >> 2;
  const int skk = (lane & 3) * 8;

  auto stage = [&](int buf, int kt) {
    const unsigned short* As = A + (long)kt * 32;
    const unsigned short* Bs = BT + (long)kt * 32;
#pragma unroll
    for (int i = 0; i < 2; ++i) {
      int c = wid * 2 + i;
      async_copy16(As + (long)(c * 16 + srow) * 1024 + skk, &Ab[buf][c * 512]);
    }
    async_copy16(Bs + (long)(wid * 16 + srow) * 16384 + skk, &Bb[buf][wid * 512]);
  };

  f32x4 acc[4][2] = {};
  stage(0, 0);
  __syncthreads();
  int buf = 0;
  const int wr = wid >> 1, wc = wid & 1;
  const int fr = lane & 15, fq = lane >> 4;
  for (int kt = 0; kt < 32; ++kt) {
    if (kt + 1 < 32) stage(buf ^ 1, kt + 1);
    const unsigned short* Ap = &Ab[buf][(wr * 64 + fr) * 32 + fq * 8];
    const unsigned short* Bp = &Bb[buf][(wc * 32 + fr) * 32 + fq * 8];
    bf16x8 af[4], bfv[2];
#pragma unroll
    for (int mi = 0; mi < 4; ++mi) af[mi] = *(const bf16x8*)(Ap + mi * 16 * 32);
#pragma unroll
    for (int ni = 0; ni < 2; ++ni) bfv[ni] = *(const bf16x8*)(Bp + ni * 16 * 32);
#pragma unroll
    for (int mi = 0; mi < 4; ++mi)
#pragma unroll
      for (int ni = 0; ni < 2; ++ni)
        acc[mi][ni] = __builtin_amdgcn_mfma_f32_16x16x32_bf16(af[mi], bfv[ni], acc[mi][ni], 0, 0, 0);
    __syncthreads();
    buf ^= 1;
  }

  float* C = out + (long)bz * 1024 * 256;
  const long m0 = (long)blockIdx.x * 128 + wr * 64;
  const long n0 = (long)blockIdx.y * 64 + wc * 32;
#pragma unroll
  for (int mi = 0; mi < 4; ++mi)
#pragma unroll
    for (int ni = 0; ni < 2; ++ni) {
      const long m = m0 + mi * 16 + fq * 4;
      const long n = n0 + ni * 16 + fr;
      f32x4 v = acc[mi][ni];
#pragma unroll
      for (int r = 0; r < 4; ++r) C[(m + r) * 256 + n] = v[r];
    }
}

// ---------------- launch ----------------
extern "C" void kernel_launch(void* const* d_in, const int* in_sizes, int n_in,
                              void* d_out, int out_size, void* d_ws, size_t ws_size,
                              hipStream_t stream) {
  const float* emb = (const float*)d_in[0];
  const int* mask = (const int*)d_in[1];
  const int* isq = (const int*)d_in[2];
  const float* qWq = (const float*)d_in[3];  const float* qbq = (const float*)d_in[4];
  const float* qWk = (const float*)d_in[5];  const float* qbk = (const float*)d_in[6];
  const float* qWv = (const float*)d_in[7];  const float* qbv = (const float*)d_in[8];
  const float* dWq = (const float*)d_in[9];  const float* dbq = (const float*)d_in[10];
  const float* dWk = (const float*)d_in[11]; const float* dbk = (const float*)d_in[12];
  const float* dWv = (const float*)d_in[13]; const float* dbv = (const float*)d_in[14];

  char* ws = (char*)d_ws;
  unsigned short* emb_bf = (unsigned short*)ws;  ws += (size_t)16384 * 768 * 2;
  unsigned short* WT     = (unsigned short*)ws;  ws += (size_t)1792 * 768 * 2;
  float*          bias   = (float*)ws;           ws += (size_t)1792 * 4;
  unsigned short* QK     = (unsigned short*)ws;  ws += (size_t)16384 * 1536 * 2;
  unsigned short* VT     = (unsigned short*)ws;  ws += (size_t)256 * 16384 * 2;
  unsigned short* attnbf = (unsigned short*)ws;  ws += (size_t)16 * 1024 * 1024 * 2;

  float* out = (float*)d_out;                    // [16,1024,256]
  float* attn = out + (size_t)16 * 1024 * 256;   // [16,1024,1024]

  (void)hipFuncSetAttribute((const void*)&logits_sm,
                            hipFuncAttributeMaxDynamicSharedMemorySize, 139264);

  hipLaunchKernelGGL(pack_emb, dim3(6144), dim3(256), 0, stream, emb, emb_bf);
  hipLaunchKernelGGL(pack_w, dim3(1792), dim3(256), 0, stream, isq,
                     qWq, qbq, qWk, qbk, qWv, qbv, dWq, dbq, dWk, dbk, dWv, dbv, WT, bias);
  // merged Q|K projection (blocks 0..1535) + V^T projection (1536..1791)
  hipLaunchKernelGGL(proj2, dim3(1792), dim3(256), 0, stream, emb_bf, WT, bias, QK, VT);
  // fused logits + mask + softmax -> attn f32 (d_out) + attnbf
  hipLaunchKernelGGL(logits_sm, dim3(16, 16), dim3(512), 139264, stream,
                     QK, mask, attn, attnbf);
  // out: per batch [1024,256] = attn_bf * V_b^T
  hipLaunchKernelGGL(gemm_pv, dim3(8, 4, 16), dim3(256), 0, stream, attnbf, VT, out);
}

// Round 5
// 184.159 us; speedup vs baseline: 1.0287x; 1.0287x over previous
//
#include <hip/hip_runtime.h>
#include <hip/hip_bf16.h>

// Problem constants: B=16, S=1024, D=768, DOUT=256
static constexpr float INV_TEMP = 0.03608439182435161f; // 1/sqrt(768)

typedef __attribute__((ext_vector_type(8))) short bf16x8;
typedef __attribute__((ext_vector_type(4))) float f32x4;
typedef __attribute__((ext_vector_type(8))) unsigned short u16x8;
typedef __attribute__((ext_vector_type(4))) unsigned short u16x4;

__device__ __forceinline__ unsigned short f2bf(float f) {
  unsigned u = __float_as_uint(f);
  u += 0x7fffu + ((u >> 16) & 1u);
  return (unsigned short)(u >> 16);
}

__device__ __forceinline__ void async_copy16(const void* g, void* lds) {
  __builtin_amdgcn_global_load_lds(
      (const __attribute__((address_space(1))) unsigned int*)g,
      (__attribute__((address_space(3))) unsigned int*)lds, 16, 0, 0);
}

// ---------------- pack kernels ----------------
__global__ __launch_bounds__(256) void pack_emb(const float* __restrict__ src,
                                                unsigned short* __restrict__ dst) {
  long i = ((long)blockIdx.x * 256 + threadIdx.x) * 8;
  float4 a = *(const float4*)(src + i);
  float4 b = *(const float4*)(src + i + 4);
  u16x8 v;
  v[0] = f2bf(a.x); v[1] = f2bf(a.y); v[2] = f2bf(a.z); v[3] = f2bf(a.w);
  v[4] = f2bf(b.x); v[5] = f2bf(b.y); v[6] = f2bf(b.z); v[7] = f2bf(b.w);
  *(u16x8*)(dst + i) = v;
}

__global__ __launch_bounds__(256) void pack_w(
    const int* __restrict__ isq_p,
    const float* qWq, const float* qbq, const float* qWk, const float* qbk,
    const float* qWv, const float* qbv,
    const float* dWq, const float* dbq, const float* dWk, const float* dbk,
    const float* dWv, const float* dbv,
    unsigned short* __restrict__ WT, float* __restrict__ bias) {
  const int n = blockIdx.x;  // 0..1791
  const int isq = *isq_p;
  const float* W; const float* bsrc; int col, srcN;
  if (n < 768)       { W = isq ? qWq : dWq; bsrc = isq ? qbq : dbq; col = n;        srcN = 768; }
  else if (n < 1536) { W = isq ? qWk : dWk; bsrc = isq ? qbk : dbk; col = n - 768;  srcN = 768; }
  else               { W = isq ? qWv : dWv; bsrc = isq ? qbv : dbv; col = n - 1536; srcN = 256; }
#pragma unroll
  for (int i = 0; i < 3; ++i) {
    int d = threadIdx.x + i * 256;
    WT[(long)n * 768 + d] = f2bf(W[(long)d * srcN + col]);
  }
  if (threadIdx.x == 0) bias[n] = bsrc[col];
}

// ======== merged projection: QK (blocks 0..1535) + VT (1536..1791) ========
// 2-phase 128x128 tile, BK=32, 4 waves, 32 KiB LDS -> 4 blocks/CU overlap.
__global__ __launch_bounds__(256) void proj2(
    const unsigned short* __restrict__ emb_bf,
    const unsigned short* __restrict__ WT,
    const float* __restrict__ bias,
    unsigned short* __restrict__ QK,
    unsigned short* __restrict__ VT) {
  __shared__ unsigned short Ab[2][128 * 32];
  __shared__ unsigned short Bb[2][128 * 32];
  const int id = blockIdx.x;
  const int tid = threadIdx.x, wid = tid >> 6, lane = tid & 63;
  const int isQK = id < 1536;
  long xa, yb;
  const unsigned short* A;
  const unsigned short* BT;
  if (isQK) {
    xa = id & 127; yb = id >> 7;                 // 128 M-tiles x 12 N-tiles
    A = emb_bf + xa * 128 * 768;
    BT = WT + yb * 128 * 768;
  } else {
    int vid = id - 1536;                          // 2 x 128
    xa = vid & 1; yb = vid >> 1;
    A = WT + (long)1536 * 768 + xa * 128 * 768;   // WvT rows
    BT = emb_bf + yb * 128 * 768;
  }
  const int srow = lane >> 2;
  const int skk = (lane & 3) * 8;

  auto stage = [&](int buf, int kt) {
    const unsigned short* As = A + (long)kt * 32;
    const unsigned short* Bs = BT + (long)kt * 32;
#pragma unroll
    for (int i = 0; i < 2; ++i) {
      int c = wid * 2 + i;  // chunk 0..7, 16 rows each
      async_copy16(As + (long)(c * 16 + srow) * 768 + skk, &Ab[buf][c * 512]);
      async_copy16(Bs + (long)(c * 16 + srow) * 768 + skk, &Bb[buf][c * 512]);
    }
  };

  f32x4 acc[4][4] = {};
  stage(0, 0);
  __syncthreads();
  int buf = 0;
  const int wr = wid >> 1, wc = wid & 1;
  const int fr = lane & 15, fq = lane >> 4;
  for (int kt = 0; kt < 24; ++kt) {
    if (kt + 1 < 24) stage(buf ^ 1, kt + 1);
    const unsigned short* Ap = &Ab[buf][(wr * 64 + fr) * 32 + fq * 8];
    const unsigned short* Bp = &Bb[buf][(wc * 64 + fr) * 32 + fq * 8];
    bf16x8 af[4], bfv[4];
#pragma unroll
    for (int mi = 0; mi < 4; ++mi) af[mi] = *(const bf16x8*)(Ap + mi * 16 * 32);
#pragma unroll
    for (int ni = 0; ni < 4; ++ni) bfv[ni] = *(const bf16x8*)(Bp + ni * 16 * 32);
#pragma unroll
    for (int mi = 0; mi < 4; ++mi)
#pragma unroll
      for (int ni = 0; ni < 4; ++ni)
        acc[mi][ni] = __builtin_amdgcn_mfma_f32_16x16x32_bf16(af[mi], bfv[ni], acc[mi][ni], 0, 0, 0);
    __syncthreads();
    buf ^= 1;
  }

#pragma unroll
  for (int mi = 0; mi < 4; ++mi) {
#pragma unroll
    for (int ni = 0; ni < 4; ++ni) {
      const long m = wr * 64 + mi * 16 + fq * 4;
      const long n = wc * 64 + ni * 16 + fr;
      f32x4 v = acc[mi][ni];
      if (isQK) {
        const long gm = xa * 128 + m, gn = yb * 128 + n;
        const float bb = bias[gn];
#pragma unroll
        for (int r = 0; r < 4; ++r) QK[(gm + r) * 1536 + gn] = f2bf(v[r] + bb);
      } else {
        const long gm = xa * 128 + m, gn = yb * 128 + n;
#pragma unroll
        for (int r = 0; r < 4; ++r)
          VT[(gm + r) * 16384 + gn] = f2bf(v[r] + bias[1536 + gm + r]);
      }
    }
  }
}

// ============ shared 256x256 8-phase K-loop (T2+T3+T4+T5) ============
// LDS: [buf(2)][region: A0,A1,B0,B1][256 x 32] bf16 = 128 KiB.
__device__ __forceinline__ void k_loop_256(
    const unsigned short* __restrict__ Apan, long lda,
    const unsigned short* __restrict__ Bpan, long ldb,
    int nk, unsigned short* smem, f32x4 (&acc)[8][4]) {
  const int tid = threadIdx.x;
  const int wid = tid >> 6, lane = tid & 63;
  const int wr = wid >> 2, wc = wid & 3;   // 2 (M) x 4 (N) wave grid
  const int fr = lane & 15, fq = lane >> 4;

  auto stage = [&](int tile, int mat, int ks, int buf) {
    const unsigned short* g = (mat ? Bpan : Apan) + (long)tile * 64 + ks * 32;
    const long ld = mat ? ldb : lda;
    unsigned short* d = smem + (((buf << 2) | (mat << 1) | ks) << 13);
#pragma unroll
    for (int i = 0; i < 2; ++i) {
      const int e = (tid + i * 512) * 8;
      const int row = e >> 5;
      const int sl = (e >> 3) & 3;
      const int ss = sl ^ ((row >> 1) & 3);
      async_copy16(g + (long)row * ld + ss * 8, d + e);
    }
  };

  const int fro = fr * 32 + ((fq ^ ((fr >> 1) & 3)) << 3);
  const int awo = fro + (wr * 128) * 32;
  const int bwo = fro + (wc * 64) * 32;

  stage(0, 0, 0, 0); stage(0, 1, 0, 0); stage(0, 0, 1, 0); stage(0, 1, 1, 0);
  if (nk > 1) {
    stage(1, 0, 0, 1); stage(1, 1, 1, 1);
    asm volatile("s_waitcnt vmcnt(4)" ::: "memory");
  } else {
    asm volatile("s_waitcnt vmcnt(0)" ::: "memory");
  }
  __builtin_amdgcn_sched_barrier(0);
  __builtin_amdgcn_s_barrier();

  for (int t = 0; t < nk; ++t) {
    const int p = t & 1;
    const unsigned short* A0 = smem + (((p << 2) | 0) << 13);
    const unsigned short* A1 = smem + (((p << 2) | 1) << 13);
    const unsigned short* B0 = smem + (((p << 2) | 2) << 13);
    const unsigned short* B1 = smem + (((p << 2) | 3) << 13);
    bf16x8 a[4], b[4];

    // phase 0: ksub0, m0..3
#pragma unroll
    for (int m = 0; m < 4; ++m) a[m] = *(const bf16x8*)(A0 + awo + m * 512);
#pragma unroll
    for (int n = 0; n < 4; ++n) b[n] = *(const bf16x8*)(B0 + bwo + n * 512);
    if (t + 1 < nk) stage(t + 1, 0, 1, (t + 1) & 1);
    __builtin_amdgcn_s_barrier();
    asm volatile("s_waitcnt lgkmcnt(0)");
    __builtin_amdgcn_sched_barrier(0);
    __builtin_amdgcn_s_setprio(1);
#pragma unroll
    for (int m = 0; m < 4; ++m)
#pragma unroll
      for (int n = 0; n < 4; ++n)
        acc[m][n] = __builtin_amdgcn_mfma_f32_16x16x32_bf16(a[m], b[n], acc[m][n], 0, 0, 0);
    __builtin_amdgcn_s_setprio(0);
    __builtin_amdgcn_sched_barrier(0);
    __builtin_amdgcn_s_barrier();

    // phase 1: ksub0, m4..7
#pragma unroll
    for (int m = 0; m < 4; ++m) a[m] = *(const bf16x8*)(A0 + awo + (4 + m) * 512);
    if (t + 1 < nk) stage(t + 1, 1, 0, (t + 1) & 1);
    __builtin_amdgcn_s_barrier();
    asm volatile("s_waitcnt lgkmcnt(0)");
    __builtin_amdgcn_sched_barrier(0);
    __builtin_amdgcn_s_setprio(1);
#pragma unroll
    for (int m = 0; m < 4; ++m)
#pragma unroll
      for (int n = 0; n < 4; ++n)
        acc[4 + m][n] = __builtin_amdgcn_mfma_f32_16x16x32_bf16(a[m], b[n], acc[4 + m][n], 0, 0, 0);
    __builtin_amdgcn_s_setprio(0);
    __builtin_amdgcn_sched_barrier(0);
    __builtin_amdgcn_s_barrier();

    // phase 2: ksub1, m0..3
#pragma unroll
    for (int m = 0; m < 4; ++m) a[m] = *(const bf16x8*)(A1 + awo + m * 512);
#pragma unroll
    for (int n = 0; n < 4; ++n) b[n] = *(const bf16x8*)(B1 + bwo + n * 512);
    if (t + 2 < nk) stage(t + 2, 0, 0, p);
    __builtin_amdgcn_s_barrier();
    asm volatile("s_waitcnt lgkmcnt(0)");
    __builtin_amdgcn_sched_barrier(0);
    __builtin_amdgcn_s_setprio(1);
#pragma unroll
    for (int m = 0; m < 4; ++m)
#pragma unroll
      for (int n = 0; n < 4; ++n)
        acc[m][n] = __builtin_amdgcn_mfma_f32_16x16x32_bf16(a[m], b[n], acc[m][n], 0, 0, 0);
    __builtin_amdgcn_s_setprio(0);
    __builtin_amdgcn_sched_barrier(0);
    __builtin_amdgcn_s_barrier();

    // phase 3: ksub1, m4..7 + tile-end counted vmcnt
#pragma unroll
    for (int m = 0; m < 4; ++m) a[m] = *(const bf16x8*)(A1 + awo + (4 + m) * 512);
    if (t + 2 < nk) stage(t + 2, 1, 1, p);
    __builtin_amdgcn_s_barrier();
    asm volatile("s_waitcnt lgkmcnt(0)");
    __builtin_amdgcn_sched_barrier(0);
    __builtin_amdgcn_s_setprio(1);
#pragma unroll
    for (int m = 0; m < 4; ++m)
#pragma unroll
      for (int n = 0; n < 4; ++n)
        acc[4 + m][n] = __builtin_amdgcn_mfma_f32_16x16x32_bf16(a[m], b[n], acc[4 + m][n], 0, 0, 0);
    __builtin_amdgcn_s_setprio(0);
    if (t < nk - 2) {
      asm volatile("s_waitcnt vmcnt(4)" ::: "memory");
    } else if (t == nk - 2) {
      asm volatile("s_waitcnt vmcnt(0)" ::: "memory");
    }
    __builtin_amdgcn_sched_barrier(0);
    __builtin_amdgcn_s_barrier();
  }
}

// ============ logits: per-batch Q*K^T * invTemp -> f32 attn ============
__global__ __launch_bounds__(512, 2) void logits256(
    const unsigned short* __restrict__ QK, float* __restrict__ attn) {
  extern __shared__ unsigned short smem[];
  const int bz = blockIdx.z;
  const unsigned short* Apan = QK + (long)bz * 1024 * 1536 + (long)blockIdx.x * 256 * 1536;
  const unsigned short* Bpan = QK + 768 + (long)bz * 1024 * 1536 + (long)blockIdx.y * 256 * 1536;
  f32x4 acc[8][4];
#pragma unroll
  for (int m = 0; m < 8; ++m)
#pragma unroll
    for (int n = 0; n < 4; ++n) acc[m][n] = f32x4{0.f, 0.f, 0.f, 0.f};

  k_loop_256(Apan, 1536, Bpan, 1536, 12, smem, acc);

  const int wid = threadIdx.x >> 6, lane = threadIdx.x & 63;
  const int wr = wid >> 2, wc = wid & 3;
  const int fr = lane & 15, fq = lane >> 4;
  float* C = attn + (long)bz * 1024 * 1024;
#pragma unroll
  for (int m = 0; m < 8; ++m)
#pragma unroll
    for (int n = 0; n < 4; ++n) {
      const long mm = (long)blockIdx.x * 256 + wr * 128 + m * 16 + fq * 4;
      const long nn = (long)blockIdx.y * 256 + wc * 64 + n * 16 + fr;
      f32x4 v = acc[m][n];
#pragma unroll
      for (int r = 0; r < 4; ++r) C[(mm + r) * 1024 + nn] = v[r] * INV_TEMP;
    }
}

// ---------------- masked row softmax + bf16 copy ----------------
__global__ __launch_bounds__(256) void softmax_rows(float* __restrict__ attn,
                                                    const int* __restrict__ mask,
                                                    unsigned short* __restrict__ attn_bf) {
  const int row = blockIdx.x;
  const int b = row >> 10;
  float* p = attn + (long)row * 1024;
  const int tid = threadIdx.x, lane = tid & 63, wid = tid >> 6;
  float4 v = ((const float4*)p)[tid];
  int4 mk = ((const int4*)(mask + b * 1024))[tid];
  v.x = mk.x ? v.x : -1e9f;
  v.y = mk.y ? v.y : -1e9f;
  v.z = mk.z ? v.z : -1e9f;
  v.w = mk.w ? v.w : -1e9f;
  float mx = fmaxf(fmaxf(v.x, v.y), fmaxf(v.z, v.w));
#pragma unroll
  for (int off = 32; off; off >>= 1) mx = fmaxf(mx, __shfl_xor(mx, off));
  __shared__ float red[4];
  if (lane == 0) red[wid] = mx;
  __syncthreads();
  mx = fmaxf(fmaxf(red[0], red[1]), fmaxf(red[2], red[3]));
  float e0 = __expf(v.x - mx), e1 = __expf(v.y - mx);
  float e2 = __expf(v.z - mx), e3 = __expf(v.w - mx);
  float s = e0 + e1 + e2 + e3;
#pragma unroll
  for (int off = 32; off; off >>= 1) s += __shfl_xor(s, off);
  __shared__ float red2[4];
  if (lane == 0) red2[wid] = s;
  __syncthreads();
  s = red2[0] + red2[1] + red2[2] + red2[3];
  const float inv = 1.0f / s;
  float4 o;
  o.x = e0 * inv; o.y = e1 * inv; o.z = e2 * inv; o.w = e3 * inv;
  ((float4*)p)[tid] = o;
  u16x4 ob;
  ob[0] = f2bf(o.x); ob[1] = f2bf(o.y); ob[2] = f2bf(o.z); ob[3] = f2bf(o.w);
  *(u16x4*)(attn_bf + (long)row * 1024 + tid * 4) = ob;
}

// ======== PV: 128x64 tiles, 512 blocks ========
__global__ __launch_bounds__(256) void gemm_pv(
    const unsigned short* __restrict__ attnbf,   // [16][1024][1024]
    const unsigned short* __restrict__ VT,       // [256][16384]
    float* __restrict__ out) {                   // [16][1024][256]
  __shared__ unsigned short Ab[2][128 * 32];
  __shared__ unsigned short Bb[2][64 * 32];
  const int tid = threadIdx.x, wid = tid >> 6, lane = tid & 63;
  const int bz = blockIdx.z;
  const unsigned short* A = attnbf + (long)bz * 1024 * 1024 + (long)blockIdx.x * 128 * 1024;
  const unsigned short* BT = VT + (long)bz * 1024 + (long)blockIdx.y * 64 * 16384;
  const int srow = lane >> 2;
  const int skk = (lane & 3) * 8;

  auto stage = [&](int buf, int kt) {
    const unsigned short* As = A + (long)kt * 32;
    const unsigned short* Bs = BT + (long)kt * 32;
#pragma unroll
    for (int i = 0; i < 2; ++i) {
      int c = wid * 2 + i;
      async_copy16(As + (long)(c * 16 + srow) * 1024 + skk, &Ab[buf][c * 512]);
    }
    async_copy16(Bs + (long)(wid * 16 + srow) * 16384 + skk, &Bb[buf][wid * 512]);
  };

  f32x4 acc[4][2] = {};
  stage(0, 0);
  __syncthreads();
  int buf = 0;
  const int wr = wid >> 1, wc = wid & 1;
  const int fr = lane & 15, fq = lane >> 4;
  for (int kt = 0; kt < 32; ++kt) {
    if (kt + 1 < 32) stage(buf ^ 1, kt + 1);
    const unsigned short* Ap = &Ab[buf][(wr * 64 + fr) * 32 + fq * 8];
    const unsigned short* Bp = &Bb[buf][(wc * 32 + fr) * 32 + fq * 8];
    bf16x8 af[4], bfv[2];
#pragma unroll
    for (int mi = 0; mi < 4; ++mi) af[mi] = *(const bf16x8*)(Ap + mi * 16 * 32);
#pragma unroll
    for (int ni = 0; ni < 2; ++ni) bfv[ni] = *(const bf16x8*)(Bp + ni * 16 * 32);
#pragma unroll
    for (int mi = 0; mi < 4; ++mi)
#pragma unroll
      for (int ni = 0; ni < 2; ++ni)
        acc[mi][ni] = __builtin_amdgcn_mfma_f32_16x16x32_bf16(af[mi], bfv[ni], acc[mi][ni], 0, 0, 0);
    __syncthreads();
    buf ^= 1;
  }

  float* C = out + (long)bz * 1024 * 256;
  const long m0 = (long)blockIdx.x * 128 + wr * 64;
  const long n0 = (long)blockIdx.y * 64 + wc * 32;
#pragma unroll
  for (int mi = 0; mi < 4; ++mi)
#pragma unroll
    for (int ni = 0; ni < 2; ++ni) {
      const long m = m0 + mi * 16 + fq * 4;
      const long n = n0 + ni * 16 + fr;
      f32x4 v = acc[mi][ni];
#pragma unroll
      for (int r = 0; r < 4; ++r) C[(m + r) * 256 + n] = v[r];
    }
}

// ---------------- launch ----------------
extern "C" void kernel_launch(void* const* d_in, const int* in_sizes, int n_in,
                              void* d_out, int out_size, void* d_ws, size_t ws_size,
                              hipStream_t stream) {
  const float* emb = (const float*)d_in[0];
  const int* mask = (const int*)d_in[1];
  const int* isq = (const int*)d_in[2];
  const float* qWq = (const float*)d_in[3];  const float* qbq = (const float*)d_in[4];
  const float* qWk = (const float*)d_in[5];  const float* qbk = (const float*)d_in[6];
  const float* qWv = (const float*)d_in[7];  const float* qbv = (const float*)d_in[8];
  const float* dWq = (const float*)d_in[9];  const float* dbq = (const float*)d_in[10];
  const float* dWk = (const float*)d_in[11]; const float* dbk = (const float*)d_in[12];
  const float* dWv = (const float*)d_in[13]; const float* dbv = (const float*)d_in[14];

  char* ws = (char*)d_ws;
  unsigned short* emb_bf = (unsigned short*)ws;  ws += (size_t)16384 * 768 * 2;
  unsigned short* WT     = (unsigned short*)ws;  ws += (size_t)1792 * 768 * 2;
  float*          bias   = (float*)ws;           ws += (size_t)1792 * 4;
  unsigned short* QK     = (unsigned short*)ws;  ws += (size_t)16384 * 1536 * 2;
  unsigned short* VT     = (unsigned short*)ws;  ws += (size_t)256 * 16384 * 2;
  unsigned short* attnbf = (unsigned short*)ws;  ws += (size_t)16 * 1024 * 1024 * 2;

  float* out = (float*)d_out;                    // [16,1024,256]
  float* attn = out + (size_t)16 * 1024 * 256;   // [16,1024,1024]

  (void)hipFuncSetAttribute((const void*)&logits256,
                            hipFuncAttributeMaxDynamicSharedMemorySize, 131072);

  hipLaunchKernelGGL(pack_emb, dim3(6144), dim3(256), 0, stream, emb, emb_bf);
  hipLaunchKernelGGL(pack_w, dim3(1792), dim3(256), 0, stream, isq,
                     qWq, qbq, qWk, qbk, qWv, qbv, dWq, dbq, dWk, dbk, dWv, dbv, WT, bias);
  // merged Q|K projection (blocks 0..1535) + V^T projection (1536..1791)
  hipLaunchKernelGGL(proj2, dim3(1792), dim3(256), 0, stream, emb_bf, WT, bias, QK, VT);
  // logits: per batch [1024,1024] = Q_b * K_b^T * invTemp -> d_out attn (f32)
  hipLaunchKernelGGL(logits256, dim3(4, 4, 16), dim3(512), 131072, stream, QK, attn);
  // masked row softmax in-place + bf16 copy
  hipLaunchKernelGGL(softmax_rows, dim3(16384), dim3(256), 0, stream, attn, mask, attnbf);
  // out: per batch [1024,256] = attn_bf * V_b^T
  hipLaunchKernelGGL(gemm_pv, dim3(8, 4, 16), dim3(256), 0, stream, attnbf, VT, out);
}